// Round 1
// baseline (307.193 us; speedup 1.0000x reference)
//
#include <hip/hip_runtime.h>

#define SEQ 4096
#define DMODEL 1024
#define HEADS 16
#define HD 64
#define NQKV 3072

typedef __attribute__((ext_vector_type(8))) __bf16 bf16x8;
typedef __attribute__((ext_vector_type(8))) short short8;
typedef __attribute__((ext_vector_type(4))) float f32x4;

__device__ __forceinline__ unsigned short f2bf(float f) {
    unsigned u = __builtin_bit_cast(unsigned, f);
    return (unsigned short)((u + 0x7fffu + ((u >> 16) & 1u)) >> 16);
}
__device__ __forceinline__ float bf2f(unsigned short h) {
    return __builtin_bit_cast(float, (unsigned)h << 16);
}

__device__ __forceinline__ void gload16(const void* g, void* l) {
    __builtin_amdgcn_global_load_lds(
        (const __attribute__((address_space(1))) unsigned int*)g,
        (__attribute__((address_space(3))) unsigned int*)l, 16, 0, 0);
}

// ---------------- fp32 -> bf16 convert ----------------
__global__ void f2bf_vec(const float* __restrict__ in, unsigned short* __restrict__ out, int n4) {
    int i = blockIdx.x * 256 + threadIdx.x;
    int stride = gridDim.x * 256;
    for (; i < n4; i += stride) {
        float4 f = reinterpret_cast<const float4*>(in)[i];
        ushort4 o;
        o.x = f2bf(f.x); o.y = f2bf(f.y); o.z = f2bf(f.z); o.w = f2bf(f.w);
        reinterpret_cast<ushort4*>(out)[i] = o;
    }
}

// ---------------- bf16 GEMM, C = A(MxK) * B(NxK)^T ----------------
// EPI 0: write bf16 scattered into qkv pack [part][h][s][64]
// EPI 1: write fp32 row-major to outF
template <int EPI>
__global__ __launch_bounds__(256) void gemm_bt(const unsigned short* __restrict__ A,
                                               const unsigned short* __restrict__ B,
                                               float* __restrict__ outF,
                                               unsigned short* __restrict__ outB,
                                               int M, int N, int K) {
    alignas(16) __shared__ unsigned short a_lds[128 * 32];
    alignas(16) __shared__ unsigned short b_lds[128 * 32];
    const int tid = threadIdx.x;
    const int wave = tid >> 6, lane = tid & 63;
    const int l16 = lane & 15, g = lane >> 4;
    const int wr = wave >> 1, wc = wave & 1;
    const int bm = blockIdx.x, bn = blockIdx.y;

    const int lrow = lane >> 2;        // 0..15 within a 16-row chunk
    const int lcol = (lane & 3) * 8;   // k-offset in elements

    const unsigned short* Ag = A + (size_t)(bm * 128 + lrow) * K + lcol;
    const unsigned short* Bg = B + (size_t)(bn * 128 + lrow) * K + lcol;

    f32x4 acc[4][4] = {};

    for (int k0 = 0; k0 < K; k0 += 32) {
#pragma unroll
        for (int j = 0; j < 2; ++j) {
            int chunk = wave * 2 + j;  // 0..7 -> rows chunk*16
            gload16(Ag + (size_t)(chunk * 16) * K + k0, a_lds + chunk * 512);
            gload16(Bg + (size_t)(chunk * 16) * K + k0, b_lds + chunk * 512);
        }
        __syncthreads();
        bf16x8 af[4], bfr[4];
#pragma unroll
        for (int m = 0; m < 4; ++m)
            af[m] = *reinterpret_cast<const bf16x8*>(a_lds + (wr * 64 + m * 16 + l16) * 32 + g * 8);
#pragma unroll
        for (int n = 0; n < 4; ++n)
            bfr[n] = *reinterpret_cast<const bf16x8*>(b_lds + (wc * 64 + n * 16 + l16) * 32 + g * 8);
#pragma unroll
        for (int m = 0; m < 4; ++m)
#pragma unroll
            for (int n = 0; n < 4; ++n)
                acc[m][n] = __builtin_amdgcn_mfma_f32_16x16x32_bf16(af[m], bfr[n], acc[m][n], 0, 0, 0);
        __syncthreads();
    }

#pragma unroll
    for (int m = 0; m < 4; ++m)
#pragma unroll
        for (int n = 0; n < 4; ++n)
#pragma unroll
            for (int r = 0; r < 4; ++r) {
                int row = bm * 128 + wr * 64 + m * 16 + g * 4 + r;
                int col = bn * 128 + wc * 64 + n * 16 + l16;
                float v = acc[m][n][r];
                if (EPI == 0) {
                    int part = col >> 10;
                    int hd = col & 1023;
                    int h = hd >> 6, d = hd & 63;
                    outB[(size_t)((part * HEADS + h) * SEQ + row) * HD + d] = f2bf(v);
                } else {
                    outF[(size_t)row * N + col] = v;
                }
            }
}

// ---------------- RoPE in place on Q,K parts (Q scaled by 1/8) ----------------
__global__ __launch_bounds__(256) void rope_kernel(unsigned short* qkv, const int* __restrict__ pos) {
    int idx = blockIdx.x * 256 + threadIdx.x;  // 2*16*4096*8 total
    int chunk = idx & 7;
    int row = idx >> 3;
    int s = row & (SEQ - 1);
    int ph = row >> 12;  // part*HEADS + h, 0..31
    float p = (float)pos[s];
    float scale = (ph < HEADS) ? 0.125f : 1.0f;
    unsigned short* base = qkv + ((size_t)ph * SEQ + s) * HD + chunk * 8;
    short8 v = *reinterpret_cast<short8*>(base);
    short8 o;
    const float k = -13.287712379549449f / 32.0f;  // -log2(10000)/32
#pragma unroll
    for (int j = 0; j < 4; ++j) {
        int i = chunk * 4 + j;
        float ang = p * exp2f((float)i * k);
        float sn, cs;
        sincosf(ang, &sn, &cs);
        float x1 = bf2f((unsigned short)v[2 * j]);
        float x2 = bf2f((unsigned short)v[2 * j + 1]);
        o[2 * j]     = (short)f2bf((x1 * cs - x2 * sn) * scale);
        o[2 * j + 1] = (short)f2bf((x1 * sn + x2 * cs) * scale);
    }
    *reinterpret_cast<short8*>(base) = o;
}

// ---------------- V transpose: [s][d] -> VT [h][d][s] ----------------
__global__ __launch_bounds__(256) void transpose_v(const unsigned short* __restrict__ qkv,
                                                   unsigned short* __restrict__ vt) {
    const int st = blockIdx.x;  // 64-row s tile
    const int h = blockIdx.y;
    __shared__ unsigned short tile[64][72];
    const unsigned short* Vg = qkv + (size_t)((2 * HEADS + h) * SEQ) * HD;
    const int tid = threadIdx.x;
#pragma unroll
    for (int j = 0; j < 2; ++j) {
        int b = (tid + j * 256) * 8;  // element index
        int row = b >> 6;
        int col = b & 63;
        short8 v = *reinterpret_cast<const short8*>(Vg + (size_t)(st * 64 + row) * HD + col);
#pragma unroll
        for (int i = 0; i < 8; ++i) tile[row][col + i] = (unsigned short)v[i];
    }
    __syncthreads();
#pragma unroll
    for (int j = 0; j < 2; ++j) {
        int b = (tid + j * 256) * 8;
        int d = b >> 6;
        int sc = b & 63;
        short8 o;
#pragma unroll
        for (int i = 0; i < 8; ++i) o[i] = (short)tile[sc + i][d];
        *reinterpret_cast<short8*>(vt + (size_t)(h * HD + d) * SEQ + st * 64 + sc) = o;
    }
}

// ---------------- causal flash attention ----------------
__global__ __launch_bounds__(256) void attn_kernel(const unsigned short* __restrict__ qkv,
                                                   const unsigned short* __restrict__ vt,
                                                   unsigned short* __restrict__ attnout) {
    const int qb = blockIdx.x;  // 64-row q tile
    const int h = blockIdx.y;
    const int tid = threadIdx.x;
    const int wave = tid >> 6, lane = tid & 63;
    const int l16 = lane & 15, g = lane >> 4;

    alignas(16) __shared__ unsigned short k_lds[64 * 64];
    alignas(16) __shared__ unsigned short v_lds[64 * 64];
    alignas(16) __shared__ unsigned short p_lds[4][16 * 64];

    const unsigned short* Qg = qkv + (size_t)((0 * HEADS + h) * SEQ) * HD;
    const unsigned short* Kg = qkv + (size_t)((1 * HEADS + h) * SEQ) * HD;
    const unsigned short* VTg = vt + (size_t)h * HD * SEQ;

    const int qbase = qb * 64 + wave * 16;
    bf16x8 qf[2];
    qf[0] = *reinterpret_cast<const bf16x8*>(Qg + (size_t)(qbase + l16) * HD + g * 8);
    qf[1] = *reinterpret_cast<const bf16x8*>(Qg + (size_t)(qbase + l16) * HD + 32 + g * 8);

    f32x4 o_acc[4] = {};
    float m_r[4], l_r[4];
#pragma unroll
    for (int r = 0; r < 4; ++r) { m_r[r] = -1e30f; l_r[r] = 0.f; }

    const float LOG2E = 1.4426950408889634f;
    char* pbase = (char*)p_lds + wave * 2048;

    for (int kt = 0; kt <= qb; ++kt) {
        __syncthreads();
        // stage K [kc][d] and VT [d][kv] tiles, XOR-swizzled rows (128B rows)
#pragma unroll
        for (int j = 0; j < 2; ++j) {
            int b = (tid + j * 256) * 16;  // byte index into 8KB tile
            int row = b >> 7;
            int col8 = (b >> 4) & 7;
            int sw = row * 128 + ((col8 ^ (row & 7)) << 4);
            *reinterpret_cast<bf16x8*>((char*)k_lds + sw) =
                *reinterpret_cast<const bf16x8*>(Kg + (size_t)(kt * 64 + row) * HD + col8 * 8);
            *reinterpret_cast<bf16x8*>((char*)v_lds + sw) =
                *reinterpret_cast<const bf16x8*>(VTg + (size_t)row * SEQ + kt * 64 + col8 * 8);
        }
        __syncthreads();

        // S = Q * K^T  (16 q-rows x 64 k-cols per wave)
        f32x4 s_acc[4] = {};
#pragma unroll
        for (int nt = 0; nt < 4; ++nt)
#pragma unroll
            for (int kk = 0; kk < 2; ++kk) {
                int row = nt * 16 + l16;
                int col8 = kk * 4 + g;
                bf16x8 kf = *reinterpret_cast<const bf16x8*>(
                    (char*)k_lds + row * 128 + ((col8 ^ (row & 7)) << 4));
                s_acc[nt] = __builtin_amdgcn_mfma_f32_16x16x32_bf16(qf[kk], kf, s_acc[nt], 0, 0, 0);
            }

        if (kt == qb) {
#pragma unroll
            for (int nt = 0; nt < 4; ++nt)
#pragma unroll
                for (int r = 0; r < 4; ++r) {
                    int kc = nt * 16 + l16;
                    int qr = wave * 16 + g * 4 + r;
                    if (kc > qr) s_acc[nt][r] = -1e30f;
                }
        }

        // online softmax (rows live in 16-lane groups; xor-reduce over lanes 1,2,4,8)
        float alpha[4];
#pragma unroll
        for (int r = 0; r < 4; ++r) {
            float mx = fmaxf(fmaxf(s_acc[0][r], s_acc[1][r]), fmaxf(s_acc[2][r], s_acc[3][r]));
#pragma unroll
            for (int msk = 1; msk < 16; msk <<= 1) mx = fmaxf(mx, __shfl_xor(mx, msk, 64));
            float mnew = fmaxf(m_r[r], mx);
            alpha[r] = exp2f((m_r[r] - mnew) * LOG2E);
            m_r[r] = mnew;
            float rs = 0.f;
#pragma unroll
            for (int nt = 0; nt < 4; ++nt) {
                float pv = exp2f((s_acc[nt][r] - mnew) * LOG2E);
                s_acc[nt][r] = pv;
                rs += pv;
            }
#pragma unroll
            for (int msk = 1; msk < 16; msk <<= 1) rs += __shfl_xor(rs, msk, 64);
            l_r[r] = l_r[r] * alpha[r] + rs;
        }
#pragma unroll
        for (int nt = 0; nt < 4; ++nt)
#pragma unroll
            for (int r = 0; r < 4; ++r) o_acc[nt][r] *= alpha[r];

        // P -> LDS (bf16, swizzled) to re-fragment as MFMA A operand
#pragma unroll
        for (int nt = 0; nt < 4; ++nt)
#pragma unroll
            for (int r = 0; r < 4; ++r) {
                int prow = g * 4 + r;
                int pcol = nt * 16 + l16;
                int c8 = pcol >> 3;
                int off = prow * 128 + ((c8 ^ (prow & 7)) << 4) + (pcol & 7) * 2;
                *reinterpret_cast<unsigned short*>(pbase + off) = f2bf(s_acc[nt][r]);
            }

        // O += P * V
#pragma unroll
        for (int nt = 0; nt < 4; ++nt)
#pragma unroll
            for (int kk = 0; kk < 2; ++kk) {
                int ac8 = kk * 4 + g;
                bf16x8 pa = *reinterpret_cast<const bf16x8*>(
                    pbase + l16 * 128 + ((ac8 ^ (l16 & 7)) << 4));
                int vrow = nt * 16 + l16;
                int vc8 = kk * 4 + g;
                bf16x8 vb = *reinterpret_cast<const bf16x8*>(
                    (char*)v_lds + vrow * 128 + ((vc8 ^ (vrow & 7)) << 4));
                o_acc[nt] = __builtin_amdgcn_mfma_f32_16x16x32_bf16(pa, vb, o_acc[nt], 0, 0, 0);
            }
    }

    // epilogue: O /= l, write attn [s][h*64+d] bf16
#pragma unroll
    for (int r = 0; r < 4; ++r) {
        float inv = 1.0f / l_r[r];
        int qrow = qb * 64 + wave * 16 + g * 4 + r;
#pragma unroll
        for (int nt = 0; nt < 4; ++nt) {
            int d = nt * 16 + l16;
            attnout[(size_t)qrow * DMODEL + h * HD + d] = f2bf(o_acc[nt][r] * inv);
        }
    }
}

extern "C" void kernel_launch(void* const* d_in, const int* in_sizes, int n_in,
                              void* d_out, int out_size, void* d_ws, size_t ws_size,
                              hipStream_t stream) {
    const float* x = (const float*)d_in[0];
    const int* pos = (const int*)d_in[1];
    const float* wqkv = (const float*)d_in[2];
    const float* wo = (const float*)d_in[3];
    float* out = (float*)d_out;

    unsigned short* xb = (unsigned short*)d_ws;                       // 4M elems
    unsigned short* wqkvb = xb + (size_t)SEQ * DMODEL;                // 3M
    unsigned short* wob = wqkvb + (size_t)NQKV * DMODEL;              // 1M
    unsigned short* qkvp = wob + (size_t)DMODEL * DMODEL;             // 12M  [3][16][4096][64]
    unsigned short* vt = qkvp + (size_t)3 * HEADS * SEQ * HD;         // 4M   [16][64][4096]
    unsigned short* attnb = vt + (size_t)HEADS * HD * SEQ;            // 4M   [4096][1024]

    f2bf_vec<<<2048, 256, 0, stream>>>(x, xb, SEQ * DMODEL / 4);
    f2bf_vec<<<2048, 256, 0, stream>>>(wqkv, wqkvb, NQKV * DMODEL / 4);
    f2bf_vec<<<1024, 256, 0, stream>>>(wo, wob, DMODEL * DMODEL / 4);

    dim3 g1(SEQ / 128, NQKV / 128);
    gemm_bt<0><<<g1, 256, 0, stream>>>(xb, wqkvb, nullptr, qkvp, SEQ, NQKV, DMODEL);

    rope_kernel<<<(2 * HEADS * SEQ * 8) / 256, 256, 0, stream>>>(qkvp, pos);
    transpose_v<<<dim3(SEQ / 64, HEADS), 256, 0, stream>>>(qkvp, vt);
    attn_kernel<<<dim3(SEQ / 64, HEADS), 256, 0, stream>>>(qkvp, vt, attnb);

    dim3 g2(SEQ / 128, DMODEL / 128);
    gemm_bt<1><<<g2, 256, 0, stream>>>(attnb, wob, out, nullptr, SEQ, DMODEL, DMODEL);
}

// Round 2
// 249.217 us; speedup vs baseline: 1.2326x; 1.2326x over previous
//
#include <hip/hip_runtime.h>

#define SEQ 4096
#define DMODEL 1024
#define HEADS 16
#define HD 64
#define NQKV 3072

typedef __attribute__((ext_vector_type(8))) __bf16 bf16x8;
typedef __attribute__((ext_vector_type(4))) __bf16 bf16x4;
typedef __attribute__((ext_vector_type(8))) short short8;
typedef __attribute__((ext_vector_type(4))) float f32x4;

__device__ __forceinline__ unsigned short f2bf(float f) {
    unsigned u = __builtin_bit_cast(unsigned, f);
    return (unsigned short)((u + 0x7fffu + ((u >> 16) & 1u)) >> 16);
}
__device__ __forceinline__ float bf2f(unsigned short h) {
    return __builtin_bit_cast(float, (unsigned)h << 16);
}

__device__ __forceinline__ void gload16(const void* g, void* l) {
    __builtin_amdgcn_global_load_lds(
        (const __attribute__((address_space(1))) unsigned int*)g,
        (__attribute__((address_space(3))) unsigned int*)l, 16, 0, 0);
}

// ---------------- fp32 -> bf16 convert ----------------
__global__ void f2bf_vec(const float* __restrict__ in, unsigned short* __restrict__ out, int n4) {
    int i = blockIdx.x * 256 + threadIdx.x;
    int stride = gridDim.x * 256;
    for (; i < n4; i += stride) {
        float4 f = reinterpret_cast<const float4*>(in)[i];
        ushort4 o;
        o.x = f2bf(f.x); o.y = f2bf(f.y); o.z = f2bf(f.z); o.w = f2bf(f.w);
        reinterpret_cast<ushort4*>(out)[i] = o;
    }
}

// ---------------- bf16 GEMM, C = A(MxK) * B(NxK)^T ----------------
template <int EPI>
__global__ __launch_bounds__(256) void gemm_bt(const unsigned short* __restrict__ A,
                                               const unsigned short* __restrict__ B,
                                               float* __restrict__ outF,
                                               unsigned short* __restrict__ outB,
                                               int M, int N, int K) {
    alignas(16) __shared__ unsigned short a_lds[128 * 32];
    alignas(16) __shared__ unsigned short b_lds[128 * 32];
    const int tid = threadIdx.x;
    const int wave = tid >> 6, lane = tid & 63;
    const int l16 = lane & 15, g = lane >> 4;
    const int wr = wave >> 1, wc = wave & 1;
    const int bm = blockIdx.x, bn = blockIdx.y;

    const int lrow = lane >> 2;
    const int lcol = (lane & 3) * 8;

    const unsigned short* Ag = A + (size_t)(bm * 128 + lrow) * K + lcol;
    const unsigned short* Bg = B + (size_t)(bn * 128 + lrow) * K + lcol;

    f32x4 acc[4][4] = {};

    for (int k0 = 0; k0 < K; k0 += 32) {
#pragma unroll
        for (int j = 0; j < 2; ++j) {
            int chunk = wave * 2 + j;
            gload16(Ag + (size_t)(chunk * 16) * K + k0, a_lds + chunk * 512);
            gload16(Bg + (size_t)(chunk * 16) * K + k0, b_lds + chunk * 512);
        }
        __syncthreads();
        bf16x8 af[4], bfr[4];
#pragma unroll
        for (int m = 0; m < 4; ++m)
            af[m] = *reinterpret_cast<const bf16x8*>(a_lds + (wr * 64 + m * 16 + l16) * 32 + g * 8);
#pragma unroll
        for (int n = 0; n < 4; ++n)
            bfr[n] = *reinterpret_cast<const bf16x8*>(b_lds + (wc * 64 + n * 16 + l16) * 32 + g * 8);
#pragma unroll
        for (int m = 0; m < 4; ++m)
#pragma unroll
            for (int n = 0; n < 4; ++n)
                acc[m][n] = __builtin_amdgcn_mfma_f32_16x16x32_bf16(af[m], bfr[n], acc[m][n], 0, 0, 0);
        __syncthreads();
    }

#pragma unroll
    for (int m = 0; m < 4; ++m)
#pragma unroll
        for (int n = 0; n < 4; ++n)
#pragma unroll
            for (int r = 0; r < 4; ++r) {
                int row = bm * 128 + wr * 64 + m * 16 + g * 4 + r;
                int col = bn * 128 + wc * 64 + n * 16 + l16;
                float v = acc[m][n][r];
                if (EPI == 0) {
                    int part = col >> 10;
                    int hd = col & 1023;
                    int h = hd >> 6, d = hd & 63;
                    outB[(size_t)((part * HEADS + h) * SEQ + row) * HD + d] = f2bf(v);
                } else {
                    outF[(size_t)row * N + col] = v;
                }
            }
}

// ---------------- RoPE in place on Q,K (Q scaled by 1/8 * log2e) ----------------
__global__ __launch_bounds__(256) void rope_kernel(unsigned short* qkv, const int* __restrict__ pos) {
    int idx = blockIdx.x * 256 + threadIdx.x;
    int chunk = idx & 7;
    int row = idx >> 3;
    int s = row & (SEQ - 1);
    int ph = row >> 12;
    float p = (float)pos[s];
    // Q gets softmax scale 1/8 AND log2(e) folded in -> scores come out in log2 domain
    float scale = (ph < HEADS) ? 0.125f * 1.4426950408889634f : 1.0f;
    unsigned short* base = qkv + ((size_t)ph * SEQ + s) * HD + chunk * 8;
    short8 v = *reinterpret_cast<short8*>(base);
    short8 o;
    const float k = -13.287712379549449f / 32.0f;
#pragma unroll
    for (int j = 0; j < 4; ++j) {
        int i = chunk * 4 + j;
        float ang = p * exp2f((float)i * k);
        float sn, cs;
        sincosf(ang, &sn, &cs);
        float x1 = bf2f((unsigned short)v[2 * j]);
        float x2 = bf2f((unsigned short)v[2 * j + 1]);
        o[2 * j]     = (short)f2bf((x1 * cs - x2 * sn) * scale);
        o[2 * j + 1] = (short)f2bf((x1 * sn + x2 * cs) * scale);
    }
    *reinterpret_cast<short8*>(base) = o;
}

// ---------------- V transpose: [s][d] -> VT [h][d][s] ----------------
__global__ __launch_bounds__(256) void transpose_v(const unsigned short* __restrict__ qkv,
                                                   unsigned short* __restrict__ vt) {
    const int st = blockIdx.x;
    const int h = blockIdx.y;
    __shared__ unsigned short tile[64][72];
    const unsigned short* Vg = qkv + (size_t)((2 * HEADS + h) * SEQ) * HD;
    const int tid = threadIdx.x;
#pragma unroll
    for (int j = 0; j < 2; ++j) {
        int b = (tid + j * 256) * 8;
        int row = b >> 6;
        int col = b & 63;
        short8 v = *reinterpret_cast<const short8*>(Vg + (size_t)(st * 64 + row) * HD + col);
#pragma unroll
        for (int i = 0; i < 8; ++i) tile[row][col + i] = (unsigned short)v[i];
    }
    __syncthreads();
#pragma unroll
    for (int j = 0; j < 2; ++j) {
        int b = (tid + j * 256) * 8;
        int d = b >> 6;
        int sc = b & 63;
        short8 o;
#pragma unroll
        for (int i = 0; i < 8; ++i) o[i] = (short)tile[sc + i][d];
        *reinterpret_cast<short8*>(vt + (size_t)(h * HD + d) * SEQ + st * 64 + sc) = o;
    }
}

// ---------------- causal flash attention (swapped-operand, 2-phase pipelined) ----------------
__global__ __launch_bounds__(256) void attn_kernel(const unsigned short* __restrict__ qkv,
                                                   const unsigned short* __restrict__ vt,
                                                   unsigned short* __restrict__ attnout) {
    // LPT: longest (largest qb) blocks dispatched first
    const int qb = (int)gridDim.x - 1 - (int)blockIdx.x;
    const int h = blockIdx.y;
    const int tid = threadIdx.x;
    const int wave = tid >> 6, lane = tid & 63;
    const int l16 = lane & 15, g = lane >> 4;

    // double-buffered K [k][d] and VT [d][kv] tiles (8KB each), per-wave P buffer
    alignas(16) __shared__ unsigned short k_lds[2][64 * 64];
    alignas(16) __shared__ unsigned short v_lds[2][64 * 64];
    alignas(16) __shared__ unsigned short p_lds[4][16 * 64];

    const unsigned short* Qg = qkv + (size_t)((0 * HEADS + h) * SEQ) * HD;
    const unsigned short* Kg = qkv + (size_t)((1 * HEADS + h) * SEQ) * HD;
    const unsigned short* VTg = vt + (size_t)h * HD * SEQ;

    // Q fragment (B-operand): lane holds Q[q = l16][d = kk*32 + g*8 .. +7]
    const int qbase = qb * 64 + wave * 16;
    bf16x8 qf[2];
    qf[0] = *reinterpret_cast<const bf16x8*>(Qg + (size_t)(qbase + l16) * HD + g * 8);
    qf[1] = *reinterpret_cast<const bf16x8*>(Qg + (size_t)(qbase + l16) * HD + 32 + g * 8);

    f32x4 o_acc[4] = {};
    float m_r = -1e30f, l_r = 0.f;

    char* pwave = (char*)p_lds + wave * 2048;
    const int rsw = (l16 & 7) << 4;  // per-lane row swizzle for p/k/v reads

    // stage tile kt into buffer b: linear LDS dest, inverse-swizzled global source
    auto STAGE = [&](int b, int kt) {
#pragma unroll
        for (int i = 0; i < 2; ++i) {
            int base = wave * 2048 + i * 1024;       // wave-uniform byte base
            int byte = base + lane * 16;
            int row = byte >> 7;
            int c8s = ((byte >> 4) & 7) ^ (row & 7);
            gload16(Kg + (size_t)(kt * 64 + row) * HD + c8s * 8, (char*)k_lds[b] + base);
            gload16(VTg + (size_t)row * SEQ + kt * 64 + c8s * 8, (char*)v_lds[b] + base);
        }
    };

    STAGE(0, 0);

    for (int kt = 0; kt <= qb; ++kt) {
        const int cur = kt & 1;
        __syncthreads();                    // drains my stage loads; all waves aligned
        if (kt < qb) STAGE(cur ^ 1, kt + 1); // prefetch flies under this tile's compute

        // S^T = K * Q : lane holds S[q = l16][k = nt*16 + g*4 + r] (log2 domain)
        f32x4 s[4] = {};
#pragma unroll
        for (int nt = 0; nt < 4; ++nt) {
            int row = nt * 16 + l16;
#pragma unroll
            for (int kk = 0; kk < 2; ++kk) {
                bf16x8 kf = *reinterpret_cast<const bf16x8*>(
                    (char*)k_lds[cur] + row * 128 + (((kk * 4 + g) << 4) ^ rsw));
                s[nt] = __builtin_amdgcn_mfma_f32_16x16x32_bf16(kf, qf[kk], s[nt], 0, 0, 0);
            }
        }

        if (kt == qb) {  // causal mask on diagonal tile
            int qrow = wave * 16 + l16;
#pragma unroll
            for (int nt = 0; nt < 4; ++nt)
#pragma unroll
                for (int r = 0; r < 4; ++r)
                    if (nt * 16 + g * 4 + r > qrow) s[nt][r] = -1e30f;
        }

        // online softmax: 16 values in-lane (one q-row), cross-group via 2 shuffles
        float mx = fmaxf(fmaxf(fmaxf(s[0][0], s[0][1]), fmaxf(s[0][2], s[0][3])),
                         fmaxf(fmaxf(s[1][0], s[1][1]), fmaxf(s[1][2], s[1][3])));
        mx = fmaxf(mx, fmaxf(fmaxf(fmaxf(s[2][0], s[2][1]), fmaxf(s[2][2], s[2][3])),
                             fmaxf(fmaxf(s[3][0], s[3][1]), fmaxf(s[3][2], s[3][3]))));
        mx = fmaxf(mx, __shfl_xor(mx, 16));
        mx = fmaxf(mx, __shfl_xor(mx, 32));
        float mnew = fmaxf(m_r, mx);
        float alpha = exp2f(m_r - mnew);
        m_r = mnew;
        float rs = 0.f;
#pragma unroll
        for (int nt = 0; nt < 4; ++nt)
#pragma unroll
            for (int r = 0; r < 4; ++r) {
                float pv = exp2f(s[nt][r] - mnew);
                s[nt][r] = pv;
                rs += pv;
            }
        rs += __shfl_xor(rs, 16);
        rs += __shfl_xor(rs, 32);
        l_r = l_r * alpha + rs;
#pragma unroll
        for (int dt = 0; dt < 4; ++dt)
#pragma unroll
            for (int r = 0; r < 4; ++r) o_acc[dt][r] *= alpha;

        // P^T pack -> per-wave LDS [q][k] (swizzled), 4x b64 writes
#pragma unroll
        for (int nt = 0; nt < 4; ++nt) {
            bf16x4 pb;
#pragma unroll
            for (int r = 0; r < 4; ++r) pb[r] = (__bf16)s[nt][r];
            *reinterpret_cast<bf16x4*>(pwave + l16 * 128 + ((nt * 32 + g * 8) ^ rsw)) = pb;
        }

        // P fragments (B-operand): lane holds P[q = l16][k = kk*32 + g*8 .. +7]
        bf16x8 pfrag[2];
#pragma unroll
        for (int kk = 0; kk < 2; ++kk)
            pfrag[kk] = *reinterpret_cast<const bf16x8*>(
                pwave + l16 * 128 + (((kk * 4 + g) << 4) ^ rsw));

        // O^T += VT * P^T : o_acc[dt][r] = O[q = l16][d = dt*16 + g*4 + r]
#pragma unroll
        for (int dt = 0; dt < 4; ++dt) {
            int row = dt * 16 + l16;
#pragma unroll
            for (int kk = 0; kk < 2; ++kk) {
                bf16x8 vf = *reinterpret_cast<const bf16x8*>(
                    (char*)v_lds[cur] + row * 128 + (((kk * 4 + g) << 4) ^ rsw));
                o_acc[dt] = __builtin_amdgcn_mfma_f32_16x16x32_bf16(vf, pfrag[kk], o_acc[dt], 0, 0, 0);
            }
        }
    }

    // epilogue: O /= l, 4x 8B stores per lane
    float inv = 1.0f / l_r;
    int q = qb * 64 + wave * 16 + l16;
#pragma unroll
    for (int dt = 0; dt < 4; ++dt) {
        ushort4 ov;
        ov.x = f2bf(o_acc[dt][0] * inv);
        ov.y = f2bf(o_acc[dt][1] * inv);
        ov.z = f2bf(o_acc[dt][2] * inv);
        ov.w = f2bf(o_acc[dt][3] * inv);
        *reinterpret_cast<ushort4*>(attnout + (size_t)q * DMODEL + h * HD + dt * 16 + g * 4) = ov;
    }
}

extern "C" void kernel_launch(void* const* d_in, const int* in_sizes, int n_in,
                              void* d_out, int out_size, void* d_ws, size_t ws_size,
                              hipStream_t stream) {
    const float* x = (const float*)d_in[0];
    const int* pos = (const int*)d_in[1];
    const float* wqkv = (const float*)d_in[2];
    const float* wo = (const float*)d_in[3];
    float* out = (float*)d_out;

    unsigned short* xb = (unsigned short*)d_ws;
    unsigned short* wqkvb = xb + (size_t)SEQ * DMODEL;
    unsigned short* wob = wqkvb + (size_t)NQKV * DMODEL;
    unsigned short* qkvp = wob + (size_t)DMODEL * DMODEL;
    unsigned short* vt = qkvp + (size_t)3 * HEADS * SEQ * HD;
    unsigned short* attnb = vt + (size_t)HEADS * HD * SEQ;

    f2bf_vec<<<2048, 256, 0, stream>>>(x, xb, SEQ * DMODEL / 4);
    f2bf_vec<<<2048, 256, 0, stream>>>(wqkv, wqkvb, NQKV * DMODEL / 4);
    f2bf_vec<<<1024, 256, 0, stream>>>(wo, wob, DMODEL * DMODEL / 4);

    dim3 g1(SEQ / 128, NQKV / 128);
    gemm_bt<0><<<g1, 256, 0, stream>>>(xb, wqkvb, nullptr, qkvp, SEQ, NQKV, DMODEL);

    rope_kernel<<<(2 * HEADS * SEQ * 8) / 256, 256, 0, stream>>>(qkvp, pos);
    transpose_v<<<dim3(SEQ / 64, HEADS), 256, 0, stream>>>(qkvp, vt);
    attn_kernel<<<dim3(SEQ / 64, HEADS), 256, 0, stream>>>(qkvp, vt, attnb);

    dim3 g2(SEQ / 128, DMODEL / 128);
    gemm_bt<1><<<g2, 256, 0, stream>>>(attnb, wob, out, nullptr, SEQ, DMODEL, DMODEL);
}

// Round 3
// 231.389 us; speedup vs baseline: 1.3276x; 1.0771x over previous
//
#include <hip/hip_runtime.h>

#define SEQ 4096
#define DMODEL 1024
#define HEADS 16
#define HD 64
#define NQKV 3072

typedef __attribute__((ext_vector_type(8))) __bf16 bf16x8;
typedef __attribute__((ext_vector_type(4))) __bf16 bf16x4;
typedef __attribute__((ext_vector_type(8))) short short8;
typedef __attribute__((ext_vector_type(4))) float f32x4;

__device__ __forceinline__ unsigned short f2bf(float f) {
    unsigned u = __builtin_bit_cast(unsigned, f);
    return (unsigned short)((u + 0x7fffu + ((u >> 16) & 1u)) >> 16);
}
__device__ __forceinline__ float bf2f(unsigned short h) {
    return __builtin_bit_cast(float, (unsigned)h << 16);
}

__device__ __forceinline__ void gload16(const void* g, void* l) {
    __builtin_amdgcn_global_load_lds(
        (const __attribute__((address_space(1))) unsigned int*)g,
        (__attribute__((address_space(3))) unsigned int*)l, 16, 0, 0);
}

// ---------------- fp32 -> bf16 convert ----------------
__global__ void f2bf_vec(const float* __restrict__ in, unsigned short* __restrict__ out, int n4) {
    int i = blockIdx.x * 256 + threadIdx.x;
    int stride = gridDim.x * 256;
    for (; i < n4; i += stride) {
        float4 f = reinterpret_cast<const float4*>(in)[i];
        ushort4 o;
        o.x = f2bf(f.x); o.y = f2bf(f.y); o.z = f2bf(f.z); o.w = f2bf(f.w);
        reinterpret_cast<ushort4*>(out)[i] = o;
    }
}

// ---------------- bf16 GEMM, C = A(MxK) * B(NxK)^T ----------------
template <int EPI>
__global__ __launch_bounds__(256) void gemm_bt(const unsigned short* __restrict__ A,
                                               const unsigned short* __restrict__ B,
                                               float* __restrict__ outF,
                                               unsigned short* __restrict__ outB,
                                               int M, int N, int K) {
    alignas(16) __shared__ unsigned short a_lds[128 * 32];
    alignas(16) __shared__ unsigned short b_lds[128 * 32];
    const int tid = threadIdx.x;
    const int wave = tid >> 6, lane = tid & 63;
    const int l16 = lane & 15, g = lane >> 4;
    const int wr = wave >> 1, wc = wave & 1;
    const int bm = blockIdx.x, bn = blockIdx.y;

    const int lrow = lane >> 2;
    const int lcol = (lane & 3) * 8;

    const unsigned short* Ag = A + (size_t)(bm * 128 + lrow) * K + lcol;
    const unsigned short* Bg = B + (size_t)(bn * 128 + lrow) * K + lcol;

    f32x4 acc[4][4] = {};

    for (int k0 = 0; k0 < K; k0 += 32) {
#pragma unroll
        for (int j = 0; j < 2; ++j) {
            int chunk = wave * 2 + j;
            gload16(Ag + (size_t)(chunk * 16) * K + k0, a_lds + chunk * 512);
            gload16(Bg + (size_t)(chunk * 16) * K + k0, b_lds + chunk * 512);
        }
        __syncthreads();
        bf16x8 af[4], bfr[4];
#pragma unroll
        for (int m = 0; m < 4; ++m)
            af[m] = *reinterpret_cast<const bf16x8*>(a_lds + (wr * 64 + m * 16 + l16) * 32 + g * 8);
#pragma unroll
        for (int n = 0; n < 4; ++n)
            bfr[n] = *reinterpret_cast<const bf16x8*>(b_lds + (wc * 64 + n * 16 + l16) * 32 + g * 8);
#pragma unroll
        for (int m = 0; m < 4; ++m)
#pragma unroll
            for (int n = 0; n < 4; ++n)
                acc[m][n] = __builtin_amdgcn_mfma_f32_16x16x32_bf16(af[m], bfr[n], acc[m][n], 0, 0, 0);
        __syncthreads();
    }

#pragma unroll
    for (int m = 0; m < 4; ++m)
#pragma unroll
        for (int n = 0; n < 4; ++n)
#pragma unroll
            for (int r = 0; r < 4; ++r) {
                int row = bm * 128 + wr * 64 + m * 16 + g * 4 + r;
                int col = bn * 128 + wc * 64 + n * 16 + l16;
                float v = acc[m][n][r];
                if (EPI == 0) {
                    int part = col >> 10;
                    int hd = col & 1023;
                    int h = hd >> 6, d = hd & 63;
                    outB[(size_t)((part * HEADS + h) * SEQ + row) * HD + d] = f2bf(v);
                } else {
                    outF[(size_t)row * N + col] = v;
                }
            }
}

// ---------------- RoPE in place on Q,K (Q scaled by 1/8 * log2e) ----------------
__global__ __launch_bounds__(256) void rope_kernel(unsigned short* qkv, const int* __restrict__ pos) {
    int idx = blockIdx.x * 256 + threadIdx.x;
    int chunk = idx & 7;
    int row = idx >> 3;
    int s = row & (SEQ - 1);
    int ph = row >> 12;
    float p = (float)pos[s];
    float scale = (ph < HEADS) ? 0.125f * 1.4426950408889634f : 1.0f;
    unsigned short* base = qkv + ((size_t)ph * SEQ + s) * HD + chunk * 8;
    short8 v = *reinterpret_cast<short8*>(base);
    short8 o;
    const float k = -13.287712379549449f / 32.0f;
#pragma unroll
    for (int j = 0; j < 4; ++j) {
        int i = chunk * 4 + j;
        float ang = p * exp2f((float)i * k);
        float sn, cs;
        sincosf(ang, &sn, &cs);
        float x1 = bf2f((unsigned short)v[2 * j]);
        float x2 = bf2f((unsigned short)v[2 * j + 1]);
        o[2 * j]     = (short)f2bf((x1 * cs - x2 * sn) * scale);
        o[2 * j + 1] = (short)f2bf((x1 * sn + x2 * cs) * scale);
    }
    *reinterpret_cast<short8*>(base) = o;
}

// ---------------- V transpose: [s][d] -> VT [h][d][s] ----------------
__global__ __launch_bounds__(256) void transpose_v(const unsigned short* __restrict__ qkv,
                                                   unsigned short* __restrict__ vt) {
    const int st = blockIdx.x;
    const int h = blockIdx.y;
    __shared__ unsigned short tile[64][72];
    const unsigned short* Vg = qkv + (size_t)((2 * HEADS + h) * SEQ) * HD;
    const int tid = threadIdx.x;
#pragma unroll
    for (int j = 0; j < 2; ++j) {
        int b = (tid + j * 256) * 8;
        int row = b >> 6;
        int col = b & 63;
        short8 v = *reinterpret_cast<const short8*>(Vg + (size_t)(st * 64 + row) * HD + col);
#pragma unroll
        for (int i = 0; i < 8; ++i) tile[row][col + i] = (unsigned short)v[i];
    }
    __syncthreads();
#pragma unroll
    for (int j = 0; j < 2; ++j) {
        int b = (tid + j * 256) * 8;
        int d = b >> 6;
        int sc = b & 63;
        short8 o;
#pragma unroll
        for (int i = 0; i < 8; ++i) o[i] = (short)tile[sc + i][d];
        *reinterpret_cast<short8*>(vt + (size_t)(h * HD + d) * SEQ + st * 64 + sc) = o;
    }
}

// ---------------- causal flash attention (swapped-operand, ones-MFMA l, defer-max) ----------------
__global__ __launch_bounds__(256) void attn_kernel(const unsigned short* __restrict__ qkv,
                                                   const unsigned short* __restrict__ vt,
                                                   unsigned short* __restrict__ attnout) {
    const int qb = (int)gridDim.x - 1 - (int)blockIdx.x;  // LPT
    const int h = blockIdx.y;
    const int tid = threadIdx.x;
    const int wave = tid >> 6, lane = tid & 63;
    const int l16 = lane & 15, g = lane >> 4;

    alignas(16) __shared__ unsigned short k_lds[2][64 * 64];
    alignas(16) __shared__ unsigned short v_lds[2][64 * 64];
    alignas(16) __shared__ unsigned short p_lds[4][16 * 64];

    const unsigned short* Qg = qkv + (size_t)((0 * HEADS + h) * SEQ) * HD;
    const unsigned short* Kg = qkv + (size_t)((1 * HEADS + h) * SEQ) * HD;
    const unsigned short* VTg = vt + (size_t)h * HD * SEQ;

    const int qbase = qb * 64 + wave * 16;
    bf16x8 qf[2];
    qf[0] = *reinterpret_cast<const bf16x8*>(Qg + (size_t)(qbase + l16) * HD + g * 8);
    qf[1] = *reinterpret_cast<const bf16x8*>(Qg + (size_t)(qbase + l16) * HD + 32 + g * 8);

    bf16x8 ones;
#pragma unroll
    for (int j = 0; j < 8; ++j) ones[j] = (__bf16)1.0f;

    f32x4 o_acc[4] = {};
    f32x4 l_acc = {};           // l accumulated by ones-MFMA; only [0] meaningful
    float m_r = -1e30f;

    char* pwave = (char*)p_lds + wave * 2048;
    const int rsw = (l16 & 7) << 4;

    auto STAGE = [&](int b, int kt) {
#pragma unroll
        for (int i = 0; i < 2; ++i) {
            int base = wave * 2048 + i * 1024;
            int byte = base + lane * 16;
            int row = byte >> 7;
            int c8s = ((byte >> 4) & 7) ^ (row & 7);
            gload16(Kg + (size_t)(kt * 64 + row) * HD + c8s * 8, (char*)k_lds[b] + base);
            gload16(VTg + (size_t)row * SEQ + kt * 64 + c8s * 8, (char*)v_lds[b] + base);
        }
    };

    STAGE(0, 0);

    for (int kt = 0; kt <= qb; ++kt) {
        const int cur = kt & 1;
        __syncthreads();
        if (kt < qb) STAGE(cur ^ 1, kt + 1);

        // S^T = K * Q : lane holds S[q = l16][k = nt*16 + g*4 + r] (log2 domain)
        f32x4 s[4] = {};
        __builtin_amdgcn_s_setprio(1);
#pragma unroll
        for (int nt = 0; nt < 4; ++nt) {
            int row = nt * 16 + l16;
#pragma unroll
            for (int kk = 0; kk < 2; ++kk) {
                bf16x8 kf = *reinterpret_cast<const bf16x8*>(
                    (char*)k_lds[cur] + row * 128 + (((kk * 4 + g) << 4) ^ rsw));
                s[nt] = __builtin_amdgcn_mfma_f32_16x16x32_bf16(kf, qf[kk], s[nt], 0, 0, 0);
            }
        }
        __builtin_amdgcn_s_setprio(0);

        if (kt == qb) {
            int qrow = wave * 16 + l16;
#pragma unroll
            for (int nt = 0; nt < 4; ++nt)
#pragma unroll
                for (int r = 0; r < 4; ++r)
                    if (nt * 16 + g * 4 + r > qrow) s[nt][r] = -1e30f;
        }

        // row max: max3-shaped tree (8 ops, depth 3) + 2 shuffles
        float t0 = fmaxf(fmaxf(s[0][0], s[0][1]), s[0][2]);
        float t1 = fmaxf(fmaxf(s[0][3], s[1][0]), s[1][1]);
        float t2 = fmaxf(fmaxf(s[1][2], s[1][3]), s[2][0]);
        float t3 = fmaxf(fmaxf(s[2][1], s[2][2]), s[2][3]);
        float t4 = fmaxf(fmaxf(s[3][0], s[3][1]), s[3][2]);
        float mx = fmaxf(fmaxf(fmaxf(t0, t1), t2), fmaxf(fmaxf(t3, t4), s[3][3]));
        mx = fmaxf(mx, __shfl_xor(mx, 16));
        mx = fmaxf(mx, __shfl_xor(mx, 32));

        // defer-max: only rescale when max grew by > 8 (log2 domain; P bounded by 2^8)
        if (__any(mx > m_r + 8.0f)) {
            float mnew = fmaxf(m_r, mx);
            float alpha = exp2f(m_r - mnew);
            m_r = mnew;
#pragma unroll
            for (int dt = 0; dt < 4; ++dt)
#pragma unroll
                for (int r = 0; r < 4; ++r) o_acc[dt][r] *= alpha;
            l_acc[0] *= alpha;
        }

#pragma unroll
        for (int nt = 0; nt < 4; ++nt)
#pragma unroll
            for (int r = 0; r < 4; ++r) s[nt][r] = exp2f(s[nt][r] - m_r);

        // P^T pack -> per-wave LDS [q][k] (swizzled), 4x b64 writes
#pragma unroll
        for (int nt = 0; nt < 4; ++nt) {
            bf16x4 pb;
#pragma unroll
            for (int r = 0; r < 4; ++r) pb[r] = (__bf16)s[nt][r];
            *reinterpret_cast<bf16x4*>(pwave + l16 * 128 + ((nt * 32 + g * 8) ^ rsw)) = pb;
        }

        bf16x8 pfrag[2];
#pragma unroll
        for (int kk = 0; kk < 2; ++kk)
            pfrag[kk] = *reinterpret_cast<const bf16x8*>(
                pwave + l16 * 128 + (((kk * 4 + g) << 4) ^ rsw));

        // O^T += VT * P^T ; l += ones * P^T (row-sum on the MFMA pipe)
        __builtin_amdgcn_s_setprio(1);
#pragma unroll
        for (int dt = 0; dt < 4; ++dt) {
            int row = dt * 16 + l16;
#pragma unroll
            for (int kk = 0; kk < 2; ++kk) {
                bf16x8 vf = *reinterpret_cast<const bf16x8*>(
                    (char*)v_lds[cur] + row * 128 + (((kk * 4 + g) << 4) ^ rsw));
                o_acc[dt] = __builtin_amdgcn_mfma_f32_16x16x32_bf16(vf, pfrag[kk], o_acc[dt], 0, 0, 0);
            }
        }
        l_acc = __builtin_amdgcn_mfma_f32_16x16x32_bf16(ones, pfrag[0], l_acc, 0, 0, 0);
        l_acc = __builtin_amdgcn_mfma_f32_16x16x32_bf16(ones, pfrag[1], l_acc, 0, 0, 0);
        __builtin_amdgcn_s_setprio(0);
    }

    // epilogue: every lane's l_acc[0] = l[q = l16]
    float inv = 1.0f / l_acc[0];
    int q = qb * 64 + wave * 16 + l16;
#pragma unroll
    for (int dt = 0; dt < 4; ++dt) {
        ushort4 ov;
        ov.x = f2bf(o_acc[dt][0] * inv);
        ov.y = f2bf(o_acc[dt][1] * inv);
        ov.z = f2bf(o_acc[dt][2] * inv);
        ov.w = f2bf(o_acc[dt][3] * inv);
        *reinterpret_cast<ushort4*>(attnout + (size_t)q * DMODEL + h * HD + dt * 16 + g * 4) = ov;
    }
}

extern "C" void kernel_launch(void* const* d_in, const int* in_sizes, int n_in,
                              void* d_out, int out_size, void* d_ws, size_t ws_size,
                              hipStream_t stream) {
    const float* x = (const float*)d_in[0];
    const int* pos = (const int*)d_in[1];
    const float* wqkv = (const float*)d_in[2];
    const float* wo = (const float*)d_in[3];
    float* out = (float*)d_out;

    unsigned short* xb = (unsigned short*)d_ws;
    unsigned short* wqkvb = xb + (size_t)SEQ * DMODEL;
    unsigned short* wob = wqkvb + (size_t)NQKV * DMODEL;
    unsigned short* qkvp = wob + (size_t)DMODEL * DMODEL;
    unsigned short* vt = qkvp + (size_t)3 * HEADS * SEQ * HD;
    unsigned short* attnb = vt + (size_t)HEADS * HD * SEQ;

    f2bf_vec<<<2048, 256, 0, stream>>>(x, xb, SEQ * DMODEL / 4);
    f2bf_vec<<<2048, 256, 0, stream>>>(wqkv, wqkvb, NQKV * DMODEL / 4);
    f2bf_vec<<<1024, 256, 0, stream>>>(wo, wob, DMODEL * DMODEL / 4);

    dim3 g1(SEQ / 128, NQKV / 128);
    gemm_bt<0><<<g1, 256, 0, stream>>>(xb, wqkvb, nullptr, qkvp, SEQ, NQKV, DMODEL);

    rope_kernel<<<(2 * HEADS * SEQ * 8) / 256, 256, 0, stream>>>(qkvp, pos);
    transpose_v<<<dim3(SEQ / 64, HEADS), 256, 0, stream>>>(qkvp, vt);
    attn_kernel<<<dim3(SEQ / 64, HEADS), 256, 0, stream>>>(qkvp, vt, attnb);

    dim3 g2(SEQ / 128, DMODEL / 128);
    gemm_bt<1><<<g2, 256, 0, stream>>>(attnb, wob, out, nullptr, SEQ, DMODEL, DMODEL);
}

// Round 4
// 185.397 us; speedup vs baseline: 1.6569x; 1.2481x over previous
//
#include <hip/hip_runtime.h>

#define SEQ 4096
#define DMODEL 1024
#define HEADS 16
#define HD 64
#define NQKV 3072

typedef __attribute__((ext_vector_type(8))) __bf16 bf16x8;
typedef __attribute__((ext_vector_type(4))) __bf16 bf16x4;
typedef __attribute__((ext_vector_type(8))) short short8;
typedef __attribute__((ext_vector_type(4))) float f32x4;

__device__ __forceinline__ unsigned short f2bf(float f) {
    unsigned u = __builtin_bit_cast(unsigned, f);
    return (unsigned short)((u + 0x7fffu + ((u >> 16) & 1u)) >> 16);
}
__device__ __forceinline__ float bf2f(unsigned short h) {
    return __builtin_bit_cast(float, (unsigned)h << 16);
}

__device__ __forceinline__ void gload16(const void* g, void* l) {
    __builtin_amdgcn_global_load_lds(
        (const __attribute__((address_space(1))) unsigned int*)g,
        (__attribute__((address_space(3))) unsigned int*)l, 16, 0, 0);
}

// ---------------- fp32 -> bf16 convert ----------------
__global__ void f2bf_vec(const float* __restrict__ in, unsigned short* __restrict__ out, int n4) {
    int i = blockIdx.x * 256 + threadIdx.x;
    int stride = gridDim.x * 256;
    for (; i < n4; i += stride) {
        float4 f = reinterpret_cast<const float4*>(in)[i];
        ushort4 o;
        o.x = f2bf(f.x); o.y = f2bf(f.y); o.z = f2bf(f.z); o.w = f2bf(f.w);
        reinterpret_cast<ushort4*>(out)[i] = o;
    }
}

// ---------------- bf16 GEMM, C = A(MxK) * B(NxK)^T ----------------
template <int EPI>
__global__ __launch_bounds__(256) void gemm_bt(const unsigned short* __restrict__ A,
                                               const unsigned short* __restrict__ B,
                                               float* __restrict__ outF,
                                               unsigned short* __restrict__ outB,
                                               int M, int N, int K) {
    alignas(16) __shared__ unsigned short a_lds[128 * 32];
    alignas(16) __shared__ unsigned short b_lds[128 * 32];
    const int tid = threadIdx.x;
    const int wave = tid >> 6, lane = tid & 63;
    const int l16 = lane & 15, g = lane >> 4;
    const int wr = wave >> 1, wc = wave & 1;
    const int bm = blockIdx.x, bn = blockIdx.y;

    const int lrow = lane >> 2;
    const int lcol = (lane & 3) * 8;

    const unsigned short* Ag = A + (size_t)(bm * 128 + lrow) * K + lcol;
    const unsigned short* Bg = B + (size_t)(bn * 128 + lrow) * K + lcol;

    f32x4 acc[4][4] = {};

    for (int k0 = 0; k0 < K; k0 += 32) {
#pragma unroll
        for (int j = 0; j < 2; ++j) {
            int chunk = wave * 2 + j;
            gload16(Ag + (size_t)(chunk * 16) * K + k0, a_lds + chunk * 512);
            gload16(Bg + (size_t)(chunk * 16) * K + k0, b_lds + chunk * 512);
        }
        __syncthreads();
        bf16x8 af[4], bfr[4];
#pragma unroll
        for (int m = 0; m < 4; ++m)
            af[m] = *reinterpret_cast<const bf16x8*>(a_lds + (wr * 64 + m * 16 + l16) * 32 + g * 8);
#pragma unroll
        for (int n = 0; n < 4; ++n)
            bfr[n] = *reinterpret_cast<const bf16x8*>(b_lds + (wc * 64 + n * 16 + l16) * 32 + g * 8);
#pragma unroll
        for (int m = 0; m < 4; ++m)
#pragma unroll
            for (int n = 0; n < 4; ++n)
                acc[m][n] = __builtin_amdgcn_mfma_f32_16x16x32_bf16(af[m], bfr[n], acc[m][n], 0, 0, 0);
        __syncthreads();
    }

#pragma unroll
    for (int m = 0; m < 4; ++m)
#pragma unroll
        for (int n = 0; n < 4; ++n)
#pragma unroll
            for (int r = 0; r < 4; ++r) {
                int row = bm * 128 + wr * 64 + m * 16 + g * 4 + r;
                int col = bn * 128 + wc * 64 + n * 16 + l16;
                float v = acc[m][n][r];
                if (EPI == 0) {
                    int part = col >> 10;
                    int hd = col & 1023;
                    int h = hd >> 6, d = hd & 63;
                    outB[(size_t)((part * HEADS + h) * SEQ + row) * HD + d] = f2bf(v);
                } else {
                    outF[(size_t)row * N + col] = v;
                }
            }
}

// ---------------- RoPE in place on Q,K (Q scaled by 1/8 * log2e) ----------------
__global__ __launch_bounds__(256) void rope_kernel(unsigned short* qkv, const int* __restrict__ pos) {
    int idx = blockIdx.x * 256 + threadIdx.x;
    int chunk = idx & 7;
    int row = idx >> 3;
    int s = row & (SEQ - 1);
    int ph = row >> 12;
    float p = (float)pos[s];
    float scale = (ph < HEADS) ? 0.125f * 1.4426950408889634f : 1.0f;
    unsigned short* base = qkv + ((size_t)ph * SEQ + s) * HD + chunk * 8;
    short8 v = *reinterpret_cast<short8*>(base);
    short8 o;
    const float k = -13.287712379549449f / 32.0f;
#pragma unroll
    for (int j = 0; j < 4; ++j) {
        int i = chunk * 4 + j;
        float ang = p * exp2f((float)i * k);
        float sn, cs;
        sincosf(ang, &sn, &cs);
        float x1 = bf2f((unsigned short)v[2 * j]);
        float x2 = bf2f((unsigned short)v[2 * j + 1]);
        o[2 * j]     = (short)f2bf((x1 * cs - x2 * sn) * scale);
        o[2 * j + 1] = (short)f2bf((x1 * sn + x2 * cs) * scale);
    }
    *reinterpret_cast<short8*>(base) = o;
}

// ---------------- V transpose: [s][d] -> VT [h][d][s] ----------------
__global__ __launch_bounds__(256) void transpose_v(const unsigned short* __restrict__ qkv,
                                                   unsigned short* __restrict__ vt) {
    const int st = blockIdx.x;
    const int h = blockIdx.y;
    __shared__ unsigned short tile[64][72];
    const unsigned short* Vg = qkv + (size_t)((2 * HEADS + h) * SEQ) * HD;
    const int tid = threadIdx.x;
#pragma unroll
    for (int j = 0; j < 2; ++j) {
        int b = (tid + j * 256) * 8;
        int row = b >> 6;
        int col = b & 63;
        short8 v = *reinterpret_cast<const short8*>(Vg + (size_t)(st * 64 + row) * HD + col);
#pragma unroll
        for (int i = 0; i < 8; ++i) tile[row][col + i] = (unsigned short)v[i];
    }
    __syncthreads();
#pragma unroll
    for (int j = 0; j < 2; ++j) {
        int b = (tid + j * 256) * 8;
        int d = b >> 6;
        int sc = b & 63;
        short8 o;
#pragma unroll
        for (int i = 0; i < 8; ++i) o[i] = (short)tile[sc + i][d];
        *reinterpret_cast<short8*>(vt + (size_t)(h * HD + d) * SEQ + st * 64 + sc) = o;
    }
}

// ---------------- causal flash attention ----------------
// QBLK=128, 8 waves; 3-buffer 2-deep counted-vmcnt pipeline; head->XCD affinity.
__global__ __launch_bounds__(512) void attn_kernel(const unsigned short* __restrict__ qkv,
                                                   const unsigned short* __restrict__ vt,
                                                   unsigned short* __restrict__ attnout) {
    // bid%8 -> XCD (heuristic): XCD x owns heads 2x,2x+1; LPT within (long qb first)
    const int bid = blockIdx.x;
    const int xcd = bid & 7;
    const int slt = bid >> 3;                 // 0..63
    const int h = xcd * 2 + (slt & 1);
    const int qb = 31 - (slt >> 1);           // q rows [qb*128, qb*128+128)
    const int last = 2 * qb + 1;              // K-tiles 0..last (64-wide)

    const int tid = threadIdx.x;
    const int wave = tid >> 6, lane = tid & 63;
    const int l16 = lane & 15, g = lane >> 4;

    alignas(16) __shared__ unsigned short k_lds[3][64 * 64];
    alignas(16) __shared__ unsigned short v_lds[3][64 * 64];
    alignas(16) __shared__ unsigned short p_lds[8][16 * 64];

    const unsigned short* Qg = qkv + (size_t)((0 * HEADS + h) * SEQ) * HD;
    const unsigned short* Kg = qkv + (size_t)((1 * HEADS + h) * SEQ) * HD;
    const unsigned short* VTg = vt + (size_t)h * HD * SEQ;

    // Q fragment (B-operand): lane holds Q[q = l16][d = kk*32 + g*8 .. +7]
    const int qbase = qb * 128 + wave * 16;
    bf16x8 qf[2];
    qf[0] = *reinterpret_cast<const bf16x8*>(Qg + (size_t)(qbase + l16) * HD + g * 8);
    qf[1] = *reinterpret_cast<const bf16x8*>(Qg + (size_t)(qbase + l16) * HD + 32 + g * 8);

    bf16x8 ones;
#pragma unroll
    for (int j = 0; j < 8; ++j) ones[j] = (__bf16)1.0f;

    f32x4 o_acc[4] = {};
    f32x4 l_acc = {};
    float m_r = -1e30f;

    char* pwave = (char*)p_lds + wave * 2048;
    const int rsw = (l16 & 7) << 4;

    // each wave stages 1KB (8 rows) of K and of VT per tile: 2 gload16/wave/tile
    auto STAGE = [&](int b, int kt) {
        int base = wave * 1024;               // wave-uniform byte base
        int byte = base + lane * 16;
        int row = byte >> 7;
        int c8s = ((byte >> 4) & 7) ^ (row & 7);
        gload16(Kg + (size_t)(kt * 64 + row) * HD + c8s * 8, (char*)k_lds[b] + base);
        gload16(VTg + (size_t)row * SEQ + kt * 64 + c8s * 8, (char*)v_lds[b] + base);
    };

    STAGE(0, 0);
    STAGE(1, 1);   // last >= 1 always (qb >= 0)

    for (int kt = 0; kt <= last; ++kt) {
        const int cur = kt % 3;
        // drain ONLY tile kt's own 2 loads; kt+1/kt+2's stay in flight across the barrier
        if (kt < last) asm volatile("s_waitcnt vmcnt(2)" ::: "memory");
        else           asm volatile("s_waitcnt vmcnt(0)" ::: "memory");
        __builtin_amdgcn_s_barrier();
        if (kt + 2 <= last) STAGE((kt + 2) % 3, kt + 2);  // safe: all waves past barrier

        // waves whose entire q-range is below this tile's k-range: nothing to add
        if (kt * 64 > qbase + 15) continue;

        // S^T = K * Q : lane holds S[q = l16][k = nt*16 + g*4 + r] (log2 domain)
        f32x4 s[4] = {};
        __builtin_amdgcn_s_setprio(1);
#pragma unroll
        for (int nt = 0; nt < 4; ++nt) {
            int row = nt * 16 + l16;
#pragma unroll
            for (int kk = 0; kk < 2; ++kk) {
                bf16x8 kf = *reinterpret_cast<const bf16x8*>(
                    (char*)k_lds[cur] + row * 128 + (((kk * 4 + g) << 4) ^ rsw));
                s[nt] = __builtin_amdgcn_mfma_f32_16x16x32_bf16(kf, qf[kk], s[nt], 0, 0, 0);
            }
        }
        __builtin_amdgcn_s_setprio(0);

        if (kt * 64 + 63 > qbase) {  // diagonal tile for this wave
            int qrow = qbase + l16;
#pragma unroll
            for (int nt = 0; nt < 4; ++nt)
#pragma unroll
                for (int r = 0; r < 4; ++r)
                    if (kt * 64 + nt * 16 + g * 4 + r > qrow) s[nt][r] = -1e30f;
        }

        // row max: tree + 2 shuffles
        float t0 = fmaxf(fmaxf(s[0][0], s[0][1]), s[0][2]);
        float t1 = fmaxf(fmaxf(s[0][3], s[1][0]), s[1][1]);
        float t2 = fmaxf(fmaxf(s[1][2], s[1][3]), s[2][0]);
        float t3 = fmaxf(fmaxf(s[2][1], s[2][2]), s[2][3]);
        float t4 = fmaxf(fmaxf(s[3][0], s[3][1]), s[3][2]);
        float mx = fmaxf(fmaxf(fmaxf(t0, t1), t2), fmaxf(fmaxf(t3, t4), s[3][3]));
        mx = fmaxf(mx, __shfl_xor(mx, 16));
        mx = fmaxf(mx, __shfl_xor(mx, 32));

        // defer-max (log2 domain, THR=8)
        if (__any(mx > m_r + 8.0f)) {
            float mnew = fmaxf(m_r, mx);
            float alpha = exp2f(m_r - mnew);
            m_r = mnew;
#pragma unroll
            for (int dt = 0; dt < 4; ++dt)
#pragma unroll
                for (int r = 0; r < 4; ++r) o_acc[dt][r] *= alpha;
            l_acc[0] *= alpha;
        }

#pragma unroll
        for (int nt = 0; nt < 4; ++nt)
#pragma unroll
            for (int r = 0; r < 4; ++r) s[nt][r] = exp2f(s[nt][r] - m_r);

        // P^T pack -> per-wave LDS (swizzled), then re-fragment
#pragma unroll
        for (int nt = 0; nt < 4; ++nt) {
            bf16x4 pb;
#pragma unroll
            for (int r = 0; r < 4; ++r) pb[r] = (__bf16)s[nt][r];
            *reinterpret_cast<bf16x4*>(pwave + l16 * 128 + ((nt * 32 + g * 8) ^ rsw)) = pb;
        }
        bf16x8 pfrag[2];
#pragma unroll
        for (int kk = 0; kk < 2; ++kk)
            pfrag[kk] = *reinterpret_cast<const bf16x8*>(
                pwave + l16 * 128 + (((kk * 4 + g) << 4) ^ rsw));

        // O^T += VT * P^T ; l += ones * P^T
        __builtin_amdgcn_s_setprio(1);
#pragma unroll
        for (int dt = 0; dt < 4; ++dt) {
            int row = dt * 16 + l16;
#pragma unroll
            for (int kk = 0; kk < 2; ++kk) {
                bf16x8 vf = *reinterpret_cast<const bf16x8*>(
                    (char*)v_lds[cur] + row * 128 + (((kk * 4 + g) << 4) ^ rsw));
                o_acc[dt] = __builtin_amdgcn_mfma_f32_16x16x32_bf16(vf, pfrag[kk], o_acc[dt], 0, 0, 0);
            }
        }
        l_acc = __builtin_amdgcn_mfma_f32_16x16x32_bf16(ones, pfrag[0], l_acc, 0, 0, 0);
        l_acc = __builtin_amdgcn_mfma_f32_16x16x32_bf16(ones, pfrag[1], l_acc, 0, 0, 0);
        __builtin_amdgcn_s_setprio(0);
    }

    // epilogue
    float inv = 1.0f / l_acc[0];
    int q = qbase + l16;
#pragma unroll
    for (int dt = 0; dt < 4; ++dt) {
        ushort4 ov;
        ov.x = f2bf(o_acc[dt][0] * inv);
        ov.y = f2bf(o_acc[dt][1] * inv);
        ov.z = f2bf(o_acc[dt][2] * inv);
        ov.w = f2bf(o_acc[dt][3] * inv);
        *reinterpret_cast<ushort4*>(attnout + (size_t)q * DMODEL + h * HD + dt * 16 + g * 4) = ov;
    }
}

extern "C" void kernel_launch(void* const* d_in, const int* in_sizes, int n_in,
                              void* d_out, int out_size, void* d_ws, size_t ws_size,
                              hipStream_t stream) {
    const float* x = (const float*)d_in[0];
    const int* pos = (const int*)d_in[1];
    const float* wqkv = (const float*)d_in[2];
    const float* wo = (const float*)d_in[3];
    float* out = (float*)d_out;

    unsigned short* xb = (unsigned short*)d_ws;
    unsigned short* wqkvb = xb + (size_t)SEQ * DMODEL;
    unsigned short* wob = wqkvb + (size_t)NQKV * DMODEL;
    unsigned short* qkvp = wob + (size_t)DMODEL * DMODEL;
    unsigned short* vt = qkvp + (size_t)3 * HEADS * SEQ * HD;
    unsigned short* attnb = vt + (size_t)HEADS * HD * SEQ;

    f2bf_vec<<<2048, 256, 0, stream>>>(x, xb, SEQ * DMODEL / 4);
    f2bf_vec<<<2048, 256, 0, stream>>>(wqkv, wqkvb, NQKV * DMODEL / 4);
    f2bf_vec<<<1024, 256, 0, stream>>>(wo, wob, DMODEL * DMODEL / 4);

    dim3 g1(SEQ / 128, NQKV / 128);
    gemm_bt<0><<<g1, 256, 0, stream>>>(xb, wqkvb, nullptr, qkvp, SEQ, NQKV, DMODEL);

    rope_kernel<<<(2 * HEADS * SEQ * 8) / 256, 256, 0, stream>>>(qkvp, pos);
    transpose_v<<<dim3(SEQ / 64, HEADS), 256, 0, stream>>>(qkvp, vt);
    attn_kernel<<<512, 512, 0, stream>>>(qkvp, vt, attnb);

    dim3 g2(SEQ / 128, DMODEL / 128);
    gemm_bt<1><<<g2, 256, 0, stream>>>(attnb, wob, out, nullptr, SEQ, DMODEL, DMODEL);
}

// Round 5
// 167.080 us; speedup vs baseline: 1.8386x; 1.1096x over previous
//
#include <hip/hip_runtime.h>

#define SEQ 4096
#define DMODEL 1024
#define HEADS 16
#define HD 64
#define NQKV 3072

typedef __attribute__((ext_vector_type(8))) __bf16 bf16x8;
typedef __attribute__((ext_vector_type(4))) __bf16 bf16x4;
typedef __attribute__((ext_vector_type(8))) short short8;
typedef __attribute__((ext_vector_type(4))) float f32x4;

__device__ __forceinline__ unsigned short f2bf(float f) {
    unsigned u = __builtin_bit_cast(unsigned, f);
    return (unsigned short)((u + 0x7fffu + ((u >> 16) & 1u)) >> 16);
}
__device__ __forceinline__ float bf2f(unsigned short h) {
    return __builtin_bit_cast(float, (unsigned)h << 16);
}

__device__ __forceinline__ void gload16(const void* g, void* l) {
    __builtin_amdgcn_global_load_lds(
        (const __attribute__((address_space(1))) unsigned int*)g,
        (__attribute__((address_space(3))) unsigned int*)l, 16, 0, 0);
}

// ---------------- fp32 -> bf16 convert ----------------
__global__ void f2bf_vec(const float* __restrict__ in, unsigned short* __restrict__ out, int n4) {
    int i = blockIdx.x * 256 + threadIdx.x;
    int stride = gridDim.x * 256;
    for (; i < n4; i += stride) {
        float4 f = reinterpret_cast<const float4*>(in)[i];
        ushort4 o;
        o.x = f2bf(f.x); o.y = f2bf(f.y); o.z = f2bf(f.z); o.w = f2bf(f.w);
        reinterpret_cast<ushort4*>(out)[i] = o;
    }
}

// ---------------- bf16 GEMM, C = A(MxK) * B(NxK)^T ----------------
template <int EPI>
__global__ __launch_bounds__(256) void gemm_bt(const unsigned short* __restrict__ A,
                                               const unsigned short* __restrict__ B,
                                               float* __restrict__ outF,
                                               unsigned short* __restrict__ outB,
                                               int M, int N, int K) {
    alignas(16) __shared__ unsigned short a_lds[128 * 32];
    alignas(16) __shared__ unsigned short b_lds[128 * 32];
    const int tid = threadIdx.x;
    const int wave = tid >> 6, lane = tid & 63;
    const int l16 = lane & 15, g = lane >> 4;
    const int wr = wave >> 1, wc = wave & 1;
    const int bm = blockIdx.x, bn = blockIdx.y;

    const int lrow = lane >> 2;
    const int lcol = (lane & 3) * 8;

    const unsigned short* Ag = A + (size_t)(bm * 128 + lrow) * K + lcol;
    const unsigned short* Bg = B + (size_t)(bn * 128 + lrow) * K + lcol;

    f32x4 acc[4][4] = {};

    for (int k0 = 0; k0 < K; k0 += 32) {
#pragma unroll
        for (int j = 0; j < 2; ++j) {
            int chunk = wave * 2 + j;
            gload16(Ag + (size_t)(chunk * 16) * K + k0, a_lds + chunk * 512);
            gload16(Bg + (size_t)(chunk * 16) * K + k0, b_lds + chunk * 512);
        }
        __syncthreads();
        bf16x8 af[4], bfr[4];
#pragma unroll
        for (int m = 0; m < 4; ++m)
            af[m] = *reinterpret_cast<const bf16x8*>(a_lds + (wr * 64 + m * 16 + l16) * 32 + g * 8);
#pragma unroll
        for (int n = 0; n < 4; ++n)
            bfr[n] = *reinterpret_cast<const bf16x8*>(b_lds + (wc * 64 + n * 16 + l16) * 32 + g * 8);
#pragma unroll
        for (int m = 0; m < 4; ++m)
#pragma unroll
            for (int n = 0; n < 4; ++n)
                acc[m][n] = __builtin_amdgcn_mfma_f32_16x16x32_bf16(af[m], bfr[n], acc[m][n], 0, 0, 0);
        __syncthreads();
    }

#pragma unroll
    for (int m = 0; m < 4; ++m)
#pragma unroll
        for (int n = 0; n < 4; ++n)
#pragma unroll
            for (int r = 0; r < 4; ++r) {
                int row = bm * 128 + wr * 64 + m * 16 + g * 4 + r;
                int col = bn * 128 + wc * 64 + n * 16 + l16;
                float v = acc[m][n][r];
                if (EPI == 0) {
                    int part = col >> 10;
                    int hd = col & 1023;
                    int h = hd >> 6, d = hd & 63;
                    outB[(size_t)((part * HEADS + h) * SEQ + row) * HD + d] = f2bf(v);
                } else {
                    outF[(size_t)row * N + col] = v;
                }
            }
}

// ---------------- RoPE in place on Q,K (Q scaled by 1/8 * log2e) ----------------
__global__ __launch_bounds__(256) void rope_kernel(unsigned short* qkv, const int* __restrict__ pos) {
    int idx = blockIdx.x * 256 + threadIdx.x;
    int chunk = idx & 7;
    int row = idx >> 3;
    int s = row & (SEQ - 1);
    int ph = row >> 12;
    float p = (float)pos[s];
    float scale = (ph < HEADS) ? 0.125f * 1.4426950408889634f : 1.0f;
    unsigned short* base = qkv + ((size_t)ph * SEQ + s) * HD + chunk * 8;
    short8 v = *reinterpret_cast<short8*>(base);
    short8 o;
    const float k = -13.287712379549449f / 32.0f;
#pragma unroll
    for (int j = 0; j < 4; ++j) {
        int i = chunk * 4 + j;
        float ang = p * exp2f((float)i * k);
        float sn, cs;
        sincosf(ang, &sn, &cs);
        float x1 = bf2f((unsigned short)v[2 * j]);
        float x2 = bf2f((unsigned short)v[2 * j + 1]);
        o[2 * j]     = (short)f2bf((x1 * cs - x2 * sn) * scale);
        o[2 * j + 1] = (short)f2bf((x1 * sn + x2 * cs) * scale);
    }
    *reinterpret_cast<short8*>(base) = o;
}

// ---------------- V transpose: [s][d] -> VT [h][d][s] ----------------
__global__ __launch_bounds__(256) void transpose_v(const unsigned short* __restrict__ qkv,
                                                   unsigned short* __restrict__ vt) {
    const int st = blockIdx.x;
    const int h = blockIdx.y;
    __shared__ unsigned short tile[64][72];
    const unsigned short* Vg = qkv + (size_t)((2 * HEADS + h) * SEQ) * HD;
    const int tid = threadIdx.x;
#pragma unroll
    for (int j = 0; j < 2; ++j) {
        int b = (tid + j * 256) * 8;
        int row = b >> 6;
        int col = b & 63;
        short8 v = *reinterpret_cast<const short8*>(Vg + (size_t)(st * 64 + row) * HD + col);
#pragma unroll
        for (int i = 0; i < 8; ++i) tile[row][col + i] = (unsigned short)v[i];
    }
    __syncthreads();
#pragma unroll
    for (int j = 0; j < 2; ++j) {
        int b = (tid + j * 256) * 8;
        int d = b >> 6;
        int sc = b & 63;
        short8 o;
#pragma unroll
        for (int i = 0; i < 8; ++i) o[i] = (short)tile[sc + i][d];
        *reinterpret_cast<short8*>(vt + (size_t)(h * HD + d) * SEQ + st * 64 + sc) = o;
    }
}

// ---------------- causal flash attention ----------------
// QBLK=128, 8 waves; 3-buffer 2-deep counted-vmcnt pipeline; head->XCD affinity;
// balanced qb pairing so every CU gets a (qb, 31-qb) pair = constant 68 tiles.
__global__ __launch_bounds__(512) void attn_kernel(const unsigned short* __restrict__ qkv,
                                                   const unsigned short* __restrict__ vt,
                                                   unsigned short* __restrict__ attnout) {
    const int bid = blockIdx.x;
    const int xcd = bid & 7;
    const int slt = bid >> 3;                 // 0..63
    const int j = slt & 31, half = slt >> 5;
    const int h = xcd * 2 + (j & 1);
    const int qb = half ? (j >> 1) : (31 - (j >> 1));  // pairs sum to 31 per CU
    const int last = 2 * qb + 1;              // K-tiles 0..last (64-wide)

    const int tid = threadIdx.x;
    const int wave = tid >> 6, lane = tid & 63;
    const int l16 = lane & 15, g = lane >> 4;

    alignas(16) __shared__ unsigned short k_lds[3][64 * 64];
    alignas(16) __shared__ unsigned short v_lds[3][64 * 64];
    alignas(16) __shared__ unsigned short p_lds[8][16 * 64];

    const unsigned short* Qg = qkv + (size_t)((0 * HEADS + h) * SEQ) * HD;
    const unsigned short* Kg = qkv + (size_t)((1 * HEADS + h) * SEQ) * HD;
    const unsigned short* VTg = vt + (size_t)h * HD * SEQ;

    const int qbase = qb * 128 + wave * 16;
    bf16x8 qf[2];
    qf[0] = *reinterpret_cast<const bf16x8*>(Qg + (size_t)(qbase + l16) * HD + g * 8);
    qf[1] = *reinterpret_cast<const bf16x8*>(Qg + (size_t)(qbase + l16) * HD + 32 + g * 8);

    bf16x8 ones;
#pragma unroll
    for (int j2 = 0; j2 < 8; ++j2) ones[j2] = (__bf16)1.0f;

    f32x4 o_acc[4] = {};
    f32x4 l_acc = {};
    float m_r = -1e30f;

    char* pwave = (char*)p_lds + wave * 2048;
    const int rsw = (l16 & 7) << 4;

    auto STAGE = [&](int b, int kt) {
        int base = wave * 1024;
        int byte = base + lane * 16;
        int row = byte >> 7;
        int c8s = ((byte >> 4) & 7) ^ (row & 7);
        gload16(Kg + (size_t)(kt * 64 + row) * HD + c8s * 8, (char*)k_lds[b] + base);
        gload16(VTg + (size_t)row * SEQ + kt * 64 + c8s * 8, (char*)v_lds[b] + base);
    };

    STAGE(0, 0);
    STAGE(1, 1);

    for (int kt = 0; kt <= last; ++kt) {
        const int cur = kt % 3;
        if (kt < last) asm volatile("s_waitcnt vmcnt(2)" ::: "memory");
        else           asm volatile("s_waitcnt vmcnt(0)" ::: "memory");
        __builtin_amdgcn_s_barrier();
        if (kt + 2 <= last) STAGE((kt + 2) % 3, kt + 2);

        if (kt * 64 > qbase + 15) continue;

        // S^T = K * Q (log2 domain)
        f32x4 s[4] = {};
        __builtin_amdgcn_s_setprio(1);
#pragma unroll
        for (int nt = 0; nt < 4; ++nt) {
            int row = nt * 16 + l16;
#pragma unroll
            for (int kk = 0; kk < 2; ++kk) {
                bf16x8 kf = *reinterpret_cast<const bf16x8*>(
                    (char*)k_lds[cur] + row * 128 + (((kk * 4 + g) << 4) ^ rsw));
                s[nt] = __builtin_amdgcn_mfma_f32_16x16x32_bf16(kf, qf[kk], s[nt], 0, 0, 0);
            }
        }
        __builtin_amdgcn_s_setprio(0);

        if (kt * 64 + 63 > qbase) {
            int qrow = qbase + l16;
#pragma unroll
            for (int nt = 0; nt < 4; ++nt)
#pragma unroll
                for (int r = 0; r < 4; ++r)
                    if (kt * 64 + nt * 16 + g * 4 + r > qrow) s[nt][r] = -1e30f;
        }

        // row max: tree + 2 shuffles
        float t0 = fmaxf(fmaxf(s[0][0], s[0][1]), s[0][2]);
        float t1 = fmaxf(fmaxf(s[0][3], s[1][0]), s[1][1]);
        float t2 = fmaxf(fmaxf(s[1][2], s[1][3]), s[2][0]);
        float t3 = fmaxf(fmaxf(s[2][1], s[2][2]), s[2][3]);
        float t4 = fmaxf(fmaxf(s[3][0], s[3][1]), s[3][2]);
        float mx = fmaxf(fmaxf(fmaxf(t0, t1), t2), fmaxf(fmaxf(t3, t4), s[3][3]));
        mx = fmaxf(mx, __shfl_xor(mx, 16));
        mx = fmaxf(mx, __shfl_xor(mx, 32));

        // defer-max (log2 domain, THR=8)
        if (__any(mx > m_r + 8.0f)) {
            float mnew = fmaxf(m_r, mx);
            float alpha = __builtin_amdgcn_exp2f(m_r - mnew);
            m_r = mnew;
#pragma unroll
            for (int dt = 0; dt < 4; ++dt)
#pragma unroll
                for (int r = 0; r < 4; ++r) o_acc[dt][r] *= alpha;
            l_acc[0] *= alpha;
        }

#pragma unroll
        for (int nt = 0; nt < 4; ++nt)
#pragma unroll
            for (int r = 0; r < 4; ++r) s[nt][r] = __builtin_amdgcn_exp2f(s[nt][r] - m_r);

        // P^T pack -> per-wave LDS (swizzled), then re-fragment
#pragma unroll
        for (int nt = 0; nt < 4; ++nt) {
            bf16x4 pb;
#pragma unroll
            for (int r = 0; r < 4; ++r) pb[r] = (__bf16)s[nt][r];
            *reinterpret_cast<bf16x4*>(pwave + l16 * 128 + ((nt * 32 + g * 8) ^ rsw)) = pb;
        }
        bf16x8 pfrag[2];
#pragma unroll
        for (int kk = 0; kk < 2; ++kk)
            pfrag[kk] = *reinterpret_cast<const bf16x8*>(
                pwave + l16 * 128 + (((kk * 4 + g) << 4) ^ rsw));

        // O^T += VT * P^T ; l += ones * P^T
        __builtin_amdgcn_s_setprio(1);
#pragma unroll
        for (int dt = 0; dt < 4; ++dt) {
            int row = dt * 16 + l16;
#pragma unroll
            for (int kk = 0; kk < 2; ++kk) {
                bf16x8 vf = *reinterpret_cast<const bf16x8*>(
                    (char*)v_lds[cur] + row * 128 + (((kk * 4 + g) << 4) ^ rsw));
                o_acc[dt] = __builtin_amdgcn_mfma_f32_16x16x32_bf16(vf, pfrag[kk], o_acc[dt], 0, 0, 0);
            }
        }
        l_acc = __builtin_amdgcn_mfma_f32_16x16x32_bf16(ones, pfrag[0], l_acc, 0, 0, 0);
        l_acc = __builtin_amdgcn_mfma_f32_16x16x32_bf16(ones, pfrag[1], l_acc, 0, 0, 0);
        __builtin_amdgcn_s_setprio(0);
    }

    // epilogue
    float inv = 1.0f / l_acc[0];
    int q = qbase + l16;
#pragma unroll
    for (int dt = 0; dt < 4; ++dt) {
        ushort4 ov;
        ov.x = f2bf(o_acc[dt][0] * inv);
        ov.y = f2bf(o_acc[dt][1] * inv);
        ov.z = f2bf(o_acc[dt][2] * inv);
        ov.w = f2bf(o_acc[dt][3] * inv);
        *reinterpret_cast<ushort4*>(attnout + (size_t)q * DMODEL + h * HD + dt * 16 + g * 4) = ov;
    }
}

extern "C" void kernel_launch(void* const* d_in, const int* in_sizes, int n_in,
                              void* d_out, int out_size, void* d_ws, size_t ws_size,
                              hipStream_t stream) {
    const float* x = (const float*)d_in[0];
    const int* pos = (const int*)d_in[1];
    const float* wqkv = (const float*)d_in[2];
    const float* wo = (const float*)d_in[3];
    float* out = (float*)d_out;

    unsigned short* xb = (unsigned short*)d_ws;
    unsigned short* wqkvb = xb + (size_t)SEQ * DMODEL;
    unsigned short* wob = wqkvb + (size_t)NQKV * DMODEL;
    unsigned short* qkvp = wob + (size_t)DMODEL * DMODEL;
    unsigned short* vt = qkvp + (size_t)3 * HEADS * SEQ * HD;
    unsigned short* attnb = vt + (size_t)HEADS * HD * SEQ;

    f2bf_vec<<<2048, 256, 0, stream>>>(x, xb, SEQ * DMODEL / 4);
    f2bf_vec<<<2048, 256, 0, stream>>>(wqkv, wqkvb, NQKV * DMODEL / 4);
    f2bf_vec<<<1024, 256, 0, stream>>>(wo, wob, DMODEL * DMODEL / 4);

    dim3 g1(SEQ / 128, NQKV / 128);
    gemm_bt<0><<<g1, 256, 0, stream>>>(xb, wqkvb, nullptr, qkvp, SEQ, NQKV, DMODEL);

    rope_kernel<<<(2 * HEADS * SEQ * 8) / 256, 256, 0, stream>>>(qkvp, pos);
    transpose_v<<<dim3(SEQ / 64, HEADS), 256, 0, stream>>>(qkvp, vt);
    attn_kernel<<<512, 512, 0, stream>>>(qkvp, vt, attnb);

    dim3 g2(SEQ / 128, DMODEL / 128);
    gemm_bt<1><<<g2, 256, 0, stream>>>(attnb, wob, out, nullptr, SEQ, DMODEL, DMODEL);
}